// Round 6
// baseline (88.358 us; speedup 1.0000x reference)
//
#include <hip/hip_runtime.h>
#include <math.h>

// ---------------------------------------------------------------------------
// out[b] = <Z0> of: [CNOT(1,0)·CNOT(0,1)·(Rot_l0 ⊗ Rot_l1)]^3 applied to
//          (RX(x0)|0>) ⊗ (RX(x1)|0>).
// Collapsed analytically to a 3x3 bilinear form:
//   out = (1, cos x0, sin x0) · G · (1, cos x1, sin x1)^T
// Single fused kernel; lane 0 of each block builds G (9 floats) into LDS.
//
// Spill history: a 64-VGPR budget (R2's (256,4) bound; R4's default-1024
// assumption) makes the ~130-float build spill -> ~38 us serial stall.
// R5 fix (kept): __launch_bounds__(256,1) + full unroll => no spills,
// bench 115 -> 85.9 us. This round: 16 elems/thread (128 B/lane) to halve
// grid-stride iteration overhead and double bytes in flight.
// ---------------------------------------------------------------------------

struct c32 { float re, im; };
__device__ __forceinline__ c32 cmul(c32 a, c32 b) { return { a.re*b.re - a.im*b.im, a.re*b.im + a.im*b.re }; }
__device__ __forceinline__ c32 cconj(c32 a) { return { a.re, -a.im }; }

__device__ __forceinline__ void build_G(const float* __restrict__ w, float* __restrict__ Gs)
{
    c32 M[4][4];
    #pragma unroll
    for (int i = 0; i < 4; ++i)
        #pragma unroll
        for (int j = 0; j < 4; ++j)
            M[i][j] = { (i == j) ? 1.f : 0.f, 0.f };

    #pragma unroll
    for (int l = 0; l < 3; ++l) {
        c32 U[2][2][2]; // [wire][row][col]
        #pragma unroll
        for (int q = 0; q < 2; ++q) {
            float phi   = w[(l*2 + q)*3 + 0];
            float theta = w[(l*2 + q)*3 + 1];
            float omega = w[(l*2 + q)*3 + 2];
            float c = __cosf(theta * 0.5f);
            float s = __sinf(theta * 0.5f);
            float ap = -0.5f * (phi + omega);   // ep = exp(i*ap)
            float am =  0.5f * (phi - omega);   // em = exp(i*am)
            c32 ep = { __cosf(ap), __sinf(ap) };
            c32 em = { __cosf(am), __sinf(am) };
            U[q][0][0] = {  ep.re * c,  ep.im * c };
            U[q][0][1] = { -em.re * s, -em.im * s };
            U[q][1][0] = {  em.re * s, -em.im * s };  // conj(em)*s
            U[q][1][1] = {  ep.re * c, -ep.im * c };  // conj(ep)*c
        }
        // A = kron(U0, U1)
        c32 A[4][4];
        #pragma unroll
        for (int j = 0; j < 2; ++j)
            #pragma unroll
            for (int k = 0; k < 2; ++k)
                #pragma unroll
                for (int jp = 0; jp < 2; ++jp)
                    #pragma unroll
                    for (int kp = 0; kp < 2; ++kp)
                        A[2*j + k][2*jp + kp] = cmul(U[0][j][jp], U[1][k][kp]);
        // CNOT(0,1): swap rows 2,3.  CNOT(1,0): swap rows 1,3.
        #pragma unroll
        for (int col = 0; col < 4; ++col) { c32 t = A[2][col]; A[2][col] = A[3][col]; A[3][col] = t; }
        #pragma unroll
        for (int col = 0; col < 4; ++col) { c32 t = A[1][col]; A[1][col] = A[3][col]; A[3][col] = t; }
        // M = A * M
        c32 NM[4][4];
        #pragma unroll
        for (int i = 0; i < 4; ++i)
            #pragma unroll
            for (int j = 0; j < 4; ++j) {
                c32 acc = {0.f, 0.f};
                #pragma unroll
                for (int k = 0; k < 4; ++k) { c32 t = cmul(A[i][k], M[k][j]); acc.re += t.re; acc.im += t.im; }
                NM[i][j] = acc;
            }
        #pragma unroll
        for (int i = 0; i < 4; ++i)
            #pragma unroll
            for (int j = 0; j < 4; ++j) M[i][j] = NM[i][j];
    }

    // H = M^dag D M, D = diag(1,1,-1,-1)
    const float Dv[4] = {1.f, 1.f, -1.f, -1.f};
    c32 H[4][4];
    #pragma unroll
    for (int a = 0; a < 4; ++a)
        #pragma unroll
        for (int b = 0; b < 4; ++b) {
            c32 acc = {0.f, 0.f};
            #pragma unroll
            for (int c = 0; c < 4; ++c) {
                c32 t = cmul(cconj(M[c][a]), M[c][b]);
                acc.re += Dv[c] * t.re;
                acc.im += Dv[c] * t.im;
            }
            H[a][b] = acc;
        }

    // phi = (1, -i, -i, -1); K_ab = Re(conj(phi_a) * phi_b * H_ab)
    const c32 ph[4] = { {1.f,0.f}, {0.f,-1.f}, {0.f,-1.f}, {-1.f,0.f} };
    float K[16];
    #pragma unroll
    for (int a = 0; a < 4; ++a)
        #pragma unroll
        for (int b = 0; b < 4; ++b) {
            c32 f = cmul(cconj(ph[a]), ph[b]);
            K[a*4 + b] = f.re * H[a][b].re - f.im * H[a][b].im;
        }

    // Collapse r^T K r (r over half-angles) to 3x3 bilinear form over
    // basis (1, cos x, sin x):
    const float P[2][2][3] = { { {0.5f, 0.5f, 0.f}, {0.f, 0.f, 0.5f} },
                               { {0.f,  0.f, 0.5f}, {0.5f,-0.5f, 0.f} } };
    #pragma unroll
    for (int p = 0; p < 3; ++p)
        #pragma unroll
        for (int q = 0; q < 3; ++q) {
            float g = 0.f;
            #pragma unroll
            for (int i = 0; i < 2; ++i)
                #pragma unroll
                for (int k = 0; k < 2; ++k)
                    #pragma unroll
                    for (int j = 0; j < 2; ++j)
                        #pragma unroll
                        for (int l = 0; l < 2; ++l)
                            g += K[(2*i + j)*4 + (2*k + l)] * P[i][k][p] * P[j][l][q];
            Gs[p*3 + q] = g;
        }
}

__global__ __launch_bounds__(256, 1) void qfused(const float* __restrict__ x,
                                                 const float* __restrict__ w,
                                                 float* __restrict__ out, int B)
{
    __shared__ float Gs[9];
    if (threadIdx.x == 0) build_G(w, Gs);
    __syncthreads();

    const float G0 = Gs[0], G1 = Gs[1], G2 = Gs[2];
    const float G3 = Gs[3], G4 = Gs[4], G5 = Gs[5];
    const float G6 = Gs[6], G7 = Gs[7], G8 = Gs[8];

    const long long nc = (long long)B >> 4;            // 16-element chunks
    const long long stride = (long long)gridDim.x * blockDim.x;
    for (long long i = (long long)blockIdx.x * blockDim.x + threadIdx.x; i < nc; i += stride) {
        const float4* xp = (const float4*)(x + 32*i);  // 128 B contiguous per lane
        float4 v[8];
        #pragma unroll
        for (int q = 0; q < 8; ++q) v[q] = xp[q];
        float res[16];
        #pragma unroll
        for (int q = 0; q < 8; ++q) {
            // v[q] = (x0, x1, x0', x1') for two consecutive elements
            float xa0 = v[q].x, xa1 = v[q].y, xb0 = v[q].z, xb1 = v[q].w;
            {
                float C0 = __cosf(xa0), S0 = __sinf(xa0);
                float C1 = __cosf(xa1), S1 = __sinf(xa1);
                float t0 = G0 + G1*C1 + G2*S1;
                float t1 = G3 + G4*C1 + G5*S1;
                float t2 = G6 + G7*C1 + G8*S1;
                res[2*q] = t0 + C0*t1 + S0*t2;
            }
            {
                float C0 = __cosf(xb0), S0 = __sinf(xb0);
                float C1 = __cosf(xb1), S1 = __sinf(xb1);
                float t0 = G0 + G1*C1 + G2*S1;
                float t1 = G3 + G4*C1 + G5*S1;
                float t2 = G6 + G7*C1 + G8*S1;
                res[2*q + 1] = t0 + C0*t1 + S0*t2;
            }
        }
        float4* op = (float4*)(out + 16*i);
        #pragma unroll
        for (int q = 0; q < 4; ++q)
            op[q] = make_float4(res[4*q], res[4*q + 1], res[4*q + 2], res[4*q + 3]);
    }

    // tail (B % 16 != 0) — B=4M is divisible by 16, kept for generality
    if (blockIdx.x == 0 && threadIdx.x == 0) {
        for (long long i = nc*16; i < B; ++i) {
            float C0 = __cosf(x[2*i]),     S0 = __sinf(x[2*i]);
            float C1 = __cosf(x[2*i + 1]), S1 = __sinf(x[2*i + 1]);
            float t0 = G0 + G1*C1 + G2*S1;
            float t1 = G3 + G4*C1 + G5*S1;
            float t2 = G6 + G7*C1 + G8*S1;
            out[i] = t0 + C0*t1 + S0*t2;
        }
    }
}

extern "C" void kernel_launch(void* const* d_in, const int* in_sizes, int n_in,
                              void* d_out, int out_size, void* d_ws, size_t ws_size,
                              hipStream_t stream)
{
    const float* x = (const float*)d_in[0];      // [B, 2]
    const float* w = (const float*)d_in[1];      // [3, 2, 3]
    float* out = (float*)d_out;                  // [B]
    const int B = in_sizes[0] / 2;

    // 512 persistent blocks = 2 blocks/CU; grid-stride covers all of B;
    // each block pays the G-build exactly once (~1.9 iterations/thread).
    qfused<<<512, 256, 0, stream>>>(x, w, out, B);
}

// Round 7
// 85.774 us; speedup vs baseline: 1.0301x; 1.0301x over previous
//
#include <hip/hip_runtime.h>
#include <math.h>

// ---------------------------------------------------------------------------
// out[b] = <Z0> of: [CNOT(1,0)·CNOT(0,1)·(Rot_l0 ⊗ Rot_l1)]^3 applied to
//          (RX(x0)|0>) ⊗ (RX(x1)|0>).
// Collapsed analytically to a 3x3 bilinear form:
//   out = (1, cos x0, sin x0) · G · (1, cos x1, sin x1)^T
// Single fused kernel; lane 0 of each block builds G (9 floats) into LDS.
//
// Spill history: a 64-VGPR budget (R2's (256,4) bound; R4's default-1024
// assumption) makes the ~130-float build spill -> ~38 us serial stall.
// Fix (kept): __launch_bounds__(256,1) + full unroll => no spills.
// R5 = 8 elems/thread = 85.9 us (best). R6's 16 elems/thread regressed to
// 88.4 us (longer register-dependency window, no loop-overhead win) ->
// reverted to the R5 configuration.
// ---------------------------------------------------------------------------

struct c32 { float re, im; };
__device__ __forceinline__ c32 cmul(c32 a, c32 b) { return { a.re*b.re - a.im*b.im, a.re*b.im + a.im*b.re }; }
__device__ __forceinline__ c32 cconj(c32 a) { return { a.re, -a.im }; }

__device__ __forceinline__ void build_G(const float* __restrict__ w, float* __restrict__ Gs)
{
    c32 M[4][4];
    #pragma unroll
    for (int i = 0; i < 4; ++i)
        #pragma unroll
        for (int j = 0; j < 4; ++j)
            M[i][j] = { (i == j) ? 1.f : 0.f, 0.f };

    #pragma unroll
    for (int l = 0; l < 3; ++l) {
        c32 U[2][2][2]; // [wire][row][col]
        #pragma unroll
        for (int q = 0; q < 2; ++q) {
            float phi   = w[(l*2 + q)*3 + 0];
            float theta = w[(l*2 + q)*3 + 1];
            float omega = w[(l*2 + q)*3 + 2];
            float c = __cosf(theta * 0.5f);
            float s = __sinf(theta * 0.5f);
            float ap = -0.5f * (phi + omega);   // ep = exp(i*ap)
            float am =  0.5f * (phi - omega);   // em = exp(i*am)
            c32 ep = { __cosf(ap), __sinf(ap) };
            c32 em = { __cosf(am), __sinf(am) };
            U[q][0][0] = {  ep.re * c,  ep.im * c };
            U[q][0][1] = { -em.re * s, -em.im * s };
            U[q][1][0] = {  em.re * s, -em.im * s };  // conj(em)*s
            U[q][1][1] = {  ep.re * c, -ep.im * c };  // conj(ep)*c
        }
        // A = kron(U0, U1)
        c32 A[4][4];
        #pragma unroll
        for (int j = 0; j < 2; ++j)
            #pragma unroll
            for (int k = 0; k < 2; ++k)
                #pragma unroll
                for (int jp = 0; jp < 2; ++jp)
                    #pragma unroll
                    for (int kp = 0; kp < 2; ++kp)
                        A[2*j + k][2*jp + kp] = cmul(U[0][j][jp], U[1][k][kp]);
        // CNOT(0,1): swap rows 2,3.  CNOT(1,0): swap rows 1,3.
        #pragma unroll
        for (int col = 0; col < 4; ++col) { c32 t = A[2][col]; A[2][col] = A[3][col]; A[3][col] = t; }
        #pragma unroll
        for (int col = 0; col < 4; ++col) { c32 t = A[1][col]; A[1][col] = A[3][col]; A[3][col] = t; }
        // M = A * M
        c32 NM[4][4];
        #pragma unroll
        for (int i = 0; i < 4; ++i)
            #pragma unroll
            for (int j = 0; j < 4; ++j) {
                c32 acc = {0.f, 0.f};
                #pragma unroll
                for (int k = 0; k < 4; ++k) { c32 t = cmul(A[i][k], M[k][j]); acc.re += t.re; acc.im += t.im; }
                NM[i][j] = acc;
            }
        #pragma unroll
        for (int i = 0; i < 4; ++i)
            #pragma unroll
            for (int j = 0; j < 4; ++j) M[i][j] = NM[i][j];
    }

    // H = M^dag D M, D = diag(1,1,-1,-1)
    const float Dv[4] = {1.f, 1.f, -1.f, -1.f};
    c32 H[4][4];
    #pragma unroll
    for (int a = 0; a < 4; ++a)
        #pragma unroll
        for (int b = 0; b < 4; ++b) {
            c32 acc = {0.f, 0.f};
            #pragma unroll
            for (int c = 0; c < 4; ++c) {
                c32 t = cmul(cconj(M[c][a]), M[c][b]);
                acc.re += Dv[c] * t.re;
                acc.im += Dv[c] * t.im;
            }
            H[a][b] = acc;
        }

    // phi = (1, -i, -i, -1); K_ab = Re(conj(phi_a) * phi_b * H_ab)
    const c32 ph[4] = { {1.f,0.f}, {0.f,-1.f}, {0.f,-1.f}, {-1.f,0.f} };
    float K[16];
    #pragma unroll
    for (int a = 0; a < 4; ++a)
        #pragma unroll
        for (int b = 0; b < 4; ++b) {
            c32 f = cmul(cconj(ph[a]), ph[b]);
            K[a*4 + b] = f.re * H[a][b].re - f.im * H[a][b].im;
        }

    // Collapse r^T K r (r over half-angles) to 3x3 bilinear form over
    // basis (1, cos x, sin x):
    const float P[2][2][3] = { { {0.5f, 0.5f, 0.f}, {0.f, 0.f, 0.5f} },
                               { {0.f,  0.f, 0.5f}, {0.5f,-0.5f, 0.f} } };
    #pragma unroll
    for (int p = 0; p < 3; ++p)
        #pragma unroll
        for (int q = 0; q < 3; ++q) {
            float g = 0.f;
            #pragma unroll
            for (int i = 0; i < 2; ++i)
                #pragma unroll
                for (int k = 0; k < 2; ++k)
                    #pragma unroll
                    for (int j = 0; j < 2; ++j)
                        #pragma unroll
                        for (int l = 0; l < 2; ++l)
                            g += K[(2*i + j)*4 + (2*k + l)] * P[i][k][p] * P[j][l][q];
            Gs[p*3 + q] = g;
        }
}

__global__ __launch_bounds__(256, 1) void qfused(const float* __restrict__ x,
                                                 const float* __restrict__ w,
                                                 float* __restrict__ out, int B)
{
    __shared__ float Gs[9];
    if (threadIdx.x == 0) build_G(w, Gs);
    __syncthreads();

    const float G0 = Gs[0], G1 = Gs[1], G2 = Gs[2];
    const float G3 = Gs[3], G4 = Gs[4], G5 = Gs[5];
    const float G6 = Gs[6], G7 = Gs[7], G8 = Gs[8];

    const long long nc = (long long)B >> 3;            // 8-element chunks
    const long long stride = (long long)gridDim.x * blockDim.x;
    for (long long i = (long long)blockIdx.x * blockDim.x + threadIdx.x; i < nc; i += stride) {
        const float4* xp = (const float4*)(x + 16*i);  // 64 B contiguous per lane
        float4 a = xp[0], b = xp[1], c = xp[2], d = xp[3];
        float x0[8] = {a.x, a.z, b.x, b.z, c.x, c.z, d.x, d.z};
        float x1[8] = {a.y, a.w, b.y, b.w, c.y, c.w, d.y, d.w};
        float res[8];
        #pragma unroll
        for (int e = 0; e < 8; ++e) {
            float C0 = __cosf(x0[e]), S0 = __sinf(x0[e]);
            float C1 = __cosf(x1[e]), S1 = __sinf(x1[e]);
            float t0 = G0 + G1*C1 + G2*S1;
            float t1 = G3 + G4*C1 + G5*S1;
            float t2 = G6 + G7*C1 + G8*S1;
            res[e] = t0 + C0*t1 + S0*t2;
        }
        float4* op = (float4*)(out + 8*i);
        op[0] = make_float4(res[0], res[1], res[2], res[3]);
        op[1] = make_float4(res[4], res[5], res[6], res[7]);
    }

    // tail (B % 8 != 0) — B=4M is divisible by 8, kept for generality
    if (blockIdx.x == 0 && threadIdx.x == 0) {
        for (long long i = nc*8; i < B; ++i) {
            float C0 = __cosf(x[2*i]),     S0 = __sinf(x[2*i]);
            float C1 = __cosf(x[2*i + 1]), S1 = __sinf(x[2*i + 1]);
            float t0 = G0 + G1*C1 + G2*S1;
            float t1 = G3 + G4*C1 + G5*S1;
            float t2 = G6 + G7*C1 + G8*S1;
            out[i] = t0 + C0*t1 + S0*t2;
        }
    }
}

extern "C" void kernel_launch(void* const* d_in, const int* in_sizes, int n_in,
                              void* d_out, int out_size, void* d_ws, size_t ws_size,
                              hipStream_t stream)
{
    const float* x = (const float*)d_in[0];      // [B, 2]
    const float* w = (const float*)d_in[1];      // [3, 2, 3]
    float* out = (float*)d_out;                  // [B]
    const int B = in_sizes[0] / 2;

    // 512 persistent blocks = 2 blocks/CU; grid-stride covers all of B;
    // each block pays the G-build exactly once.
    qfused<<<512, 256, 0, stream>>>(x, w, out, B);
}